// Round 4
// baseline (788.392 us; speedup 1.0000x reference)
//
#include <hip/hip_runtime.h>
#include <hip/hip_bf16.h>
#include <math.h>

#define BB 8
#define TT 1024
#define CC 64
#define HH 8
#define DH 8
#define NLAY 4
#define VV 32000
#define FF 256
#define NR (BB*TT)                 // 8192
#define NLOGIT 262144000           // NR*VV
#define NCB 125                    // 32000/256 col-chunks

typedef unsigned short u16;
typedef unsigned int u32;
typedef __attribute__((ext_vector_type(8))) short short8v;
typedef __attribute__((ext_vector_type(4))) float f32x4;
typedef __attribute__((ext_vector_type(2))) float f32x2;

__device__ __forceinline__ float b2f(u16 u){
  union { float f; u32 i; } c; c.i = ((u32)u) << 16; return c.f;
}
__device__ __forceinline__ u16 f2b(float f){
  union { float f; u32 i; } c; c.f = f;
  u32 x = c.i;
  return (u16)((x + 0x7FFF + ((x >> 16) & 1)) >> 16);
}
__device__ __forceinline__ u32 pack2(float lo, float hi){
  return (u32)f2b(lo) | ((u32)f2b(hi) << 16);
}
// dtype probe via 64-lane ballot on ln1_g (~N(1,0.02)): bf16 -> all 64 high
// bytes 0x3F; f32 -> only odd u16s (~32). Threshold 48.
__device__ __forceinline__ int probe_bf16(const void* ln1g){
  const u16* lp = (const u16*)ln1g;
  unsigned long long m = __ballot((lp[threadIdx.x & 63] >> 8) == 0x3F);
  return (__popcll(m) > 48) ? 1 : 0;
}

// ---------------- convert float inputs -> f32 ws + Wout transpose, one dispatch ----------------
struct ConvArgs {
  const void* src[18];
  float* dst[18];
  int n[18];
  int blkoff[19];
};
__global__ void __launch_bounds__(256) k_convtrans(ConvArgs a, const void* __restrict__ wsrc,
                                                   const void* __restrict__ ln1g, u16* __restrict__ wt){
  __shared__ float ws_[64][65];
  int isb = probe_bf16(ln1g);
  int nconv = a.blkoff[18];
  int tid = threadIdx.x;
  if ((int)blockIdx.x < nconv){
    int bid = blockIdx.x;
    int t = 0;
    while (bid >= a.blkoff[t + 1]) t++;
    int base = (bid - a.blkoff[t]) * 1024 + tid;
    const u16* s16 = (const u16*)a.src[t];
    const float* s32 = (const float*)a.src[t];
    float* d = a.dst[t];
    int n = a.n[t];
    #pragma unroll
    for (int e = 0; e < 4; e++){
      int i = base + e * 256;
      if (i < n) d[i] = isb ? b2f(s16[i]) : s32[i];
    }
  } else {
    int v0 = (blockIdx.x - nconv) * 64;
    const u16* s16 = (const u16*)wsrc;
    const float* s32 = (const float*)wsrc;
    int vl = tid & 63;
    #pragma unroll
    for (int kk = 0; kk < 16; kk++){
      int k = kk * 4 + (tid >> 6);
      size_t idx = (size_t)k * VV + v0 + vl;
      ws_[vl][k] = isb ? b2f(s16[idx]) : s32[idx];
    }
    __syncthreads();
    #pragma unroll
    for (int pass = 0; pass < 16; pass++){
      int v2 = pass * 4 + (tid >> 6);
      int k = tid & 63;
      wt[(size_t)(v0 + v2) * 64 + k] = f2b(ws_[v2][k]);
    }
  }
}

// ---------------- embedding (reads raw tok/pos with in-kernel dtype) ----------------
__global__ void k_embed(const int* __restrict__ x, const void* __restrict__ tokr,
                        const void* __restrict__ posr, const void* __restrict__ ln1g,
                        float* __restrict__ h){
  int isb = probe_bf16(ln1g);
  int i = blockIdx.x * 256 + threadIdx.x;
  int r = i >> 6, c = i & 63;
  int t = r & (TT - 1);
  size_t ti = (size_t)x[r] * 64 + c;
  size_t pi = (size_t)t * 64 + c;
  float tv = isb ? b2f(((const u16*)tokr)[ti]) : ((const float*)tokr)[ti];
  float pv = isb ? b2f(((const u16*)posr)[pi]) : ((const float*)posr)[pi];
  h[i] = tv + pv;
}

// ---------------- qkv projection -> bf16 (q scaled, k permuted, v transposed) ----------------
__global__ void k_qkv(const float* __restrict__ h,
                      const float* __restrict__ wq, const float* __restrict__ bq,
                      const float* __restrict__ wk, const float* __restrict__ bk,
                      const float* __restrict__ wv, const float* __restrict__ bv,
                      u16* __restrict__ q16, u16* __restrict__ kp16, u16* __restrict__ vt16){
  __shared__ float hs[4][64];
  int tid = threadIdx.x;
  int row0 = blockIdx.x * 4;
  hs[tid >> 6][tid & 63] = h[row0 * 64 + tid];
  __syncthreads();
  int rr = tid >> 6, o = tid & 63;
  int head = o >> 3, d = o & 7;
  int row = row0 + rr;
  int b = row >> 10, t = row & (TT - 1);
  float aq = bq[head * 8 + d], ak = bk[head * 8 + d], av = bv[head * 8 + d];
  #pragma unroll
  for (int c = 0; c < 64; c++){
    float hv = hs[rr][c];
    aq += hv * wq[(head * 64 + c) * 8 + d];
    ak += hv * wk[(head * 64 + c) * 8 + d];
    av += hv * wv[(head * 64 + c) * 8 + d];
  }
  int bh = b * HH + head;
  q16[((size_t)bh * TT + t) * 8 + d] = f2b(aq * 0.35355339059327378f);  // fold 1/sqrt(8)
  int i = t * 8 + d;                                  // faithful reshape(B,H,D,T)
  kp16[((size_t)bh * TT + (i & 1023)) * 8 + (i >> 10)] = f2b(ak);
  vt16[((size_t)bh * 8 + d) * TT + t] = f2b(av);
}

// ---------------- fused layer: MFMA attn + LN1 + res + LN2 + FFN + res ----------------
__global__ void __launch_bounds__(512) k_layer(const u16* __restrict__ q16, const u16* __restrict__ kp16,
                                               const u16* __restrict__ vt16,
                                               const float* __restrict__ g1, const float* __restrict__ be1,
                                               const float* __restrict__ g2, const float* __restrict__ be2,
                                               const float* __restrict__ w1, const float* __restrict__ b1,
                                               const float* __restrict__ w2, const float* __restrict__ b2,
                                               float* __restrict__ h, u16* __restrict__ hbo, int last){
  __shared__ float ot[16][64];        // attn out, then hres
  __shared__ float z[16][64];         // LN2 output
  __shared__ float a[16][256];        // FFN hidden
  int tid = threadIdx.x;
  int w = tid >> 6;                  // head / wave
  int lane = tid & 63;
  int lr = lane & 15, lg = lane >> 4;
  int b = blockIdx.y;
  int bh = b * HH + w;
  int tb = blockIdx.x * 16;
  int t_g = tb + lr;

  // ---- phase 1: attention (wave w = head w), rows tb..tb+15 ----
  short8v qf = {0,0,0,0,0,0,0,0};
  if (lg == 0) qf = *(const short8v*)(q16 + ((size_t)bh * TT + tb + lr) * 8);

  float m = -1e30f, l = 0.f;
  f32x4 o = {0.f, 0.f, 0.f, 0.f};
  int nchunk = (tb >> 5) + 1;

  for (int c = 0; c < nchunk; c++){
    int s0 = c * 32;
    bool skipB = (s0 + 16 > tb + 15);
    short8v kA = {0,0,0,0,0,0,0,0}, kB = {0,0,0,0,0,0,0,0};
    if (lg == 0){
      kA = *(const short8v*)(kp16 + ((size_t)bh * TT + s0 + lr) * 8);
      if (!skipB) kB = *(const short8v*)(kp16 + ((size_t)bh * TT + s0 + 16 + lr) * 8);
    }
    f32x4 sA = __builtin_amdgcn_mfma_f32_16x16x32_bf16(kA, qf, (f32x4){0.f,0.f,0.f,0.f}, 0, 0, 0);
    f32x4 sB;
    if (!skipB)
      sB = __builtin_amdgcn_mfma_f32_16x16x32_bf16(kB, qf, (f32x4){0.f,0.f,0.f,0.f}, 0, 0, 0);
    else
      sB = (f32x4){-1e30f, -1e30f, -1e30f, -1e30f};

    if (s0 + 15 > tb){
      #pragma unroll
      for (int r = 0; r < 4; r++) if (s0 + lg * 4 + r > t_g) sA[r] = -1e30f;
    }
    if (!skipB && s0 + 31 > tb){
      #pragma unroll
      for (int r = 0; r < 4; r++) if (s0 + 16 + lg * 4 + r > t_g) sB[r] = -1e30f;
    }

    float tm = fmaxf(fmaxf(fmaxf(sA[0], sA[1]), fmaxf(sA[2], sA[3])),
                     fmaxf(fmaxf(sB[0], sB[1]), fmaxf(sB[2], sB[3])));
    tm = fmaxf(tm, __shfl_xor(tm, 16, 64));
    tm = fmaxf(tm, __shfl_xor(tm, 32, 64));
    float mn = fmaxf(m, tm);
    float fac = __expf(m - mn);
    l *= fac;
    {
      float f0 = __shfl(fac, lg * 4 + 0, 64);
      float f1 = __shfl(fac, lg * 4 + 1, 64);
      float f2 = __shfl(fac, lg * 4 + 2, 64);
      float f3 = __shfl(fac, lg * 4 + 3, 64);
      o[0] *= f0; o[1] *= f1; o[2] *= f2; o[3] *= f3;
    }
    f32x4 pA, pB;
    #pragma unroll
    for (int r = 0; r < 4; r++){ pA[r] = __expf(sA[r] - mn); pB[r] = __expf(sB[r] - mn); }
    float ls = pA[0] + pA[1] + pA[2] + pA[3] + pB[0] + pB[1] + pB[2] + pB[3];
    ls += __shfl_xor(ls, 16, 64);
    ls += __shfl_xor(ls, 32, 64);
    l += ls;
    m = mn;

    u32 a0 = pack2(pA[0], pA[1]), a1 = pack2(pA[2], pA[3]);
    u32 b0 = pack2(pB[0], pB[1]), b1v = pack2(pB[2], pB[3]);
    int src0 = ((2 * lg) & 3) * 16 + lr;
    int src1 = src0 + 16;
    u32 A0 = __shfl((int)a0, src0, 64), A1 = __shfl((int)a1, src0, 64);
    u32 A2 = __shfl((int)a0, src1, 64), A3 = __shfl((int)a1, src1, 64);
    u32 B0 = __shfl((int)b0, src0, 64), B1 = __shfl((int)b1v, src0, 64);
    u32 B2 = __shfl((int)b0, src1, 64), B3 = __shfl((int)b1v, src1, 64);
    union { u32 u[4]; short8v v; } pu;
    if (lg < 2){ pu.u[0] = A0; pu.u[1] = A1; pu.u[2] = A2; pu.u[3] = A3; }
    else       { pu.u[0] = B0; pu.u[1] = B1; pu.u[2] = B2; pu.u[3] = B3; }

    short8v vf = {0,0,0,0,0,0,0,0};
    if (lr < 8) vf = *(const short8v*)(vt16 + ((size_t)bh * 8 + lr) * TT + s0 + lg * 8);

    o = __builtin_amdgcn_mfma_f32_16x16x32_bf16(pu.v, vf, o, 0, 0, 0);
  }

  float linv = 1.f / l;
  float i0 = __shfl(linv, lg * 4 + 0, 64);
  float i1 = __shfl(linv, lg * 4 + 1, 64);
  float i2 = __shfl(linv, lg * 4 + 2, 64);
  float i3 = __shfl(linv, lg * 4 + 3, 64);
  if (lr < 8){
    ot[lg * 4 + 0][w * 8 + lr] = o[0] * i0;
    ot[lg * 4 + 1][w * 8 + lr] = o[1] * i1;
    ot[lg * 4 + 2][w * 8 + lr] = o[2] * i2;
    ot[lg * 4 + 3][w * 8 + lr] = o[3] * i3;
  }
  __syncthreads();

  // ---- phase 2: LN1 + residual -> hres (in ot), LN2 -> z ----
  #pragma unroll
  for (int pass = 0; pass < 2; pass++){
    int rl = w + pass * 8;
    float x = ot[rl][lane];
    float s = x, sq = x * x;
    for (int msk = 32; msk; msk >>= 1){
      s += __shfl_xor(s, msk, 64);
      sq += __shfl_xor(sq, msk, 64);
    }
    float mu = s * (1.f / 64);
    float var = sq * (1.f / 64) - mu * mu;
    float rstd = rsqrtf(fmaxf(var, 0.f) + 1e-5f);
    float hres = h[((size_t)b * TT + tb + rl) * 64 + lane] + (x - mu) * rstd * g1[lane] + be1[lane];
    ot[rl][lane] = hres;
    float s2 = hres, sq2 = hres * hres;
    for (int msk = 32; msk; msk >>= 1){
      s2 += __shfl_xor(s2, msk, 64);
      sq2 += __shfl_xor(sq2, msk, 64);
    }
    float mu2 = s2 * (1.f / 64);
    float var2 = sq2 * (1.f / 64) - mu2 * mu2;
    float rstd2 = rsqrtf(fmaxf(var2, 0.f) + 1e-5f);
    z[rl][lane] = (hres - mu2) * rstd2 * g2[lane] + be2[lane];
  }
  __syncthreads();

  // ---- phase 3: hidden = relu(z @ W1 + b1), thread -> (row, 8 hidden) ----
  {
    int row = tid >> 5;
    int j0 = (tid & 31) * 8;
    float acc[8];
    #pragma unroll
    for (int i = 0; i < 8; i++) acc[i] = b1[j0 + i];
    for (int c = 0; c < 64; c++){
      float zv = z[row][c];
      const f32x4* wv = (const f32x4*)(w1 + c * 256 + j0);
      f32x4 w0 = wv[0], w1v = wv[1];
      #pragma unroll
      for (int i = 0; i < 4; i++) acc[i] += zv * w0[i];
      #pragma unroll
      for (int i = 0; i < 4; i++) acc[4 + i] += zv * w1v[i];
    }
    #pragma unroll
    for (int i = 0; i < 8; i++) a[row][j0 + i] = fmaxf(acc[i], 0.f);
  }
  __syncthreads();

  // ---- phase 4: h = hres + hidden @ W2 + b2, thread -> (row, 2 cols) ----
  {
    int row = tid >> 5;
    int c0 = (tid & 31) * 2;
    float acc0 = b2[c0], acc1 = b2[c0 + 1];
    for (int k = 0; k < 256; k++){
      float av = a[row][k];
      f32x2 wv = *(const f32x2*)(w2 + k * 64 + c0);
      acc0 += av * wv[0];
      acc1 += av * wv[1];
    }
    size_t gi = ((size_t)b * TT + tb + row) * 64 + c0;
    float h0 = ot[row][c0] + acc0;
    float h1 = ot[row][c0 + 1] + acc1;
    h[gi] = h0;
    h[gi + 1] = h1;
    if (last){
      hbo[gi] = f2b(h0);
      hbo[gi + 1] = f2b(h1);
    }
  }
}

// ---------------- logits^T-frag GEMM: mfma(W,h) -> f32x4 NT stores + softmax partials ----------------
__global__ void __launch_bounds__(256) k_logits(const u16* __restrict__ hb, const u16* __restrict__ wt,
                                                const float* __restrict__ bout, float* __restrict__ logits,
                                                float2* __restrict__ part){
  int tid = threadIdx.x;
  int wave = tid >> 6, lane = tid & 63;
  int lr = lane & 15, lg = lane >> 4;
  int row0 = blockIdx.x * 64;            // x fastest: consecutive blocks share W-tile
  int cb = blockIdx.y;
  int colw = cb * 256 + wave * 64;

  short8v hf[4][2];
  #pragma unroll
  for (int ri = 0; ri < 4; ri++)
    #pragma unroll
    for (int kk = 0; kk < 2; kk++)
      hf[ri][kk] = *(const short8v*)(hb + (row0 + ri * 16 + lr) * 64 + kk * 32 + lg * 8);

  short8v wfr[4][2];
  #pragma unroll
  for (int vi = 0; vi < 4; vi++)
    #pragma unroll
    for (int kk = 0; kk < 2; kk++)
      wfr[vi][kk] = *(const short8v*)(wt + (size_t)(colw + vi * 16 + lr) * 64 + kk * 32 + lg * 8);

  f32x4 acc[4][4];
  #pragma unroll
  for (int ri = 0; ri < 4; ri++)
    #pragma unroll
    for (int vi = 0; vi < 4; vi++)
      acc[ri][vi] = (f32x4){0.f, 0.f, 0.f, 0.f};

  #pragma unroll
  for (int ri = 0; ri < 4; ri++){
    #pragma unroll
    for (int vi = 0; vi < 4; vi++){
      acc[ri][vi] = __builtin_amdgcn_mfma_f32_16x16x32_bf16(wfr[vi][0], hf[ri][0], acc[ri][vi], 0, 0, 0);
      acc[ri][vi] = __builtin_amdgcn_mfma_f32_16x16x32_bf16(wfr[vi][1], hf[ri][1], acc[ri][vi], 0, 0, 0);
    }
  }

  f32x4 bo[4];
  #pragma unroll
  for (int vi = 0; vi < 4; vi++)
    bo[vi] = *(const f32x4*)(bout + colw + vi * 16 + lg * 4);

  __shared__ float2 wml[4][64];
  #pragma unroll
  for (int ri = 0; ri < 4; ri++){
    f32x4 vals[4];
    #pragma unroll
    for (int vi = 0; vi < 4; vi++){
      vals[vi] = acc[ri][vi] + bo[vi];
      __builtin_nontemporal_store(vals[vi],
        (f32x4*)(logits + (size_t)(row0 + ri * 16 + lr) * VV + colw + vi * 16 + lg * 4));
    }
    float mx = -1e30f;
    #pragma unroll
    for (int vi = 0; vi < 4; vi++)
      #pragma unroll
      for (int r = 0; r < 4; r++) mx = fmaxf(mx, vals[vi][r]);
    mx = fmaxf(mx, __shfl_xor(mx, 16, 64));
    mx = fmaxf(mx, __shfl_xor(mx, 32, 64));
    float sume = 0.f;
    #pragma unroll
    for (int vi = 0; vi < 4; vi++)
      #pragma unroll
      for (int r = 0; r < 4; r++) sume += __expf(vals[vi][r] - mx);
    sume += __shfl_xor(sume, 16, 64);
    sume += __shfl_xor(sume, 32, 64);
    if (lg == 0) wml[wave][ri * 16 + lr] = make_float2(mx, sume);
  }
  __syncthreads();
  if (tid < 64){
    float M = -1e30f;
    #pragma unroll
    for (int w = 0; w < 4; w++) M = fmaxf(M, wml[w][tid].x);
    float L = 0.f;
    #pragma unroll
    for (int w = 0; w < 4; w++){
      float2 p = wml[w][tid];
      L += p.y * __expf(p.x - M);
    }
    part[(size_t)cb * NR + row0 + tid] = make_float2(M, L);
  }
}

// ---------------- loss reduction ----------------
__global__ void k_loss(const float2* __restrict__ part, const float* __restrict__ logits,
                       const int* __restrict__ tgt, float* __restrict__ lpart){
  int row = blockIdx.x * 64 + (threadIdx.x & 63);
  float M = -1e30f;
  for (int j = 0; j < NCB; j++) M = fmaxf(M, part[(size_t)j * NR + row].x);
  float L = 0.f;
  for (int j = 0; j < NCB; j++){
    float2 p = part[(size_t)j * NR + row];
    L += p.y * __expf(p.x - M);
  }
  float lse = M + __logf(L);
  float tl = logits[(size_t)row * VV + tgt[row]];
  float nll = lse - tl;
  for (int msk = 32; msk; msk >>= 1) nll += __shfl_xor(nll, msk, 64);
  if ((threadIdx.x & 63) == 0) lpart[blockIdx.x] = nll;
}
__global__ void k_loss2(const float* __restrict__ lpart, float* __restrict__ out){
  int lane = threadIdx.x & 63;
  float s = lpart[lane] + lpart[lane + 64];
  for (int msk = 32; msk; msk >>= 1) s += __shfl_xor(s, msk, 64);
  if (lane == 0) out[NLOGIT] = s * (1.f / NR);
}

extern "C" void kernel_launch(void* const* d_in, const int* in_sizes, int n_in,
                              void* d_out, int out_size, void* d_ws, size_t ws_size,
                              hipStream_t stream){
  (void)in_sizes; (void)n_in; (void)out_size; (void)ws_size;
  const int* x = (const int*)d_in[0];
  const int* targets = (const int*)d_in[1];
  float* out = (float*)d_out;

  // tok(0)/pos(1) read raw by k_embed; Wout(16) by transpose path.
  static const int WN[18] = {0, 0, 16384, 256, 16384, 256, 16384, 256,
                             256, 256, 256, 256, 65536, 1024, 65536, 256, 0, 32000};
  char* ws = (char*)d_ws;
  size_t off = 0;
  auto alloc = [&](size_t bytes) -> void* {
    void* p = ws + off;
    off += (bytes + 255) & ~(size_t)255;
    return p;
  };
  float* wf[18];
  for (int i = 0; i < 18; i++) wf[i] = (float*)alloc((size_t)(WN[i] ? WN[i] : 1) * 4);
  float* h     = (float*)alloc((size_t)NR * 64 * 4);
  u16* q16     = (u16*)alloc((size_t)NR * 64 * 2);
  u16* kp16    = (u16*)alloc((size_t)NR * 64 * 2);
  u16* vt16    = (u16*)alloc((size_t)NR * 64 * 2);
  u16* hb      = (u16*)alloc((size_t)NR * 64 * 2);
  u16* wt16    = (u16*)alloc((size_t)2048000 * 2);
  float2* part = (float2*)alloc((size_t)NCB * NR * 8);
  float* lpart = (float*)alloc(128 * 4);

  ConvArgs ca;
  int blk = 0;
  for (int i = 0; i < 18; i++){
    ca.src[i] = d_in[2 + i];
    ca.dst[i] = wf[i];
    ca.n[i] = WN[i];
    ca.blkoff[i] = blk;
    blk += (WN[i] + 1023) / 1024;
  }
  ca.blkoff[18] = blk;
  hipLaunchKernelGGL(k_convtrans, dim3(blk + 500), dim3(256), 0, stream, ca, d_in[18], d_in[10], wt16);
  hipLaunchKernelGGL(k_embed, dim3(2048), dim3(256), 0, stream, x, d_in[2], d_in[3], d_in[10], h);

  for (int l = 0; l < NLAY; l++){
    hipLaunchKernelGGL(k_qkv, dim3(2048), dim3(256), 0, stream, h,
                       wf[2] + l * 4096, wf[3] + l * 64,
                       wf[4] + l * 4096, wf[5] + l * 64,
                       wf[6] + l * 4096, wf[7] + l * 64,
                       q16, kp16, vt16);
    hipLaunchKernelGGL(k_layer, dim3(64, 8), dim3(512), 0, stream, q16, kp16, vt16,
                       wf[8] + l * 64, wf[9] + l * 64,
                       wf[10] + l * 64, wf[11] + l * 64,
                       wf[12] + l * 16384, wf[13] + l * 256,
                       wf[14] + l * 16384, wf[15] + l * 64,
                       h, hb, (l == NLAY - 1) ? 1 : 0);
  }

  hipLaunchKernelGGL(k_logits, dim3(128, NCB), dim3(256), 0, stream, hb, wt16, wf[17], out, part);
  hipLaunchKernelGGL(k_loss, dim3(128), dim3(64), 0, stream, part, out, targets, lpart);
  hipLaunchKernelGGL(k_loss2, dim3(1), dim3(64), 0, stream, lpart, out);
}

// Round 5
// 731.434 us; speedup vs baseline: 1.0779x; 1.0779x over previous
//
#include <hip/hip_runtime.h>
#include <hip/hip_bf16.h>
#include <math.h>

#define BB 8
#define TT 1024
#define CC 64
#define HH 8
#define DH 8
#define NLAY 4
#define VV 32000
#define FF 256
#define NR (BB*TT)                 // 8192
#define NLOGIT 262144000           // NR*VV
#define NCB 125                    // 32000/256 col-chunks

typedef unsigned short u16;
typedef unsigned int u32;
typedef __attribute__((ext_vector_type(8))) short short8v;
typedef __attribute__((ext_vector_type(4))) float f32x4;

__device__ __forceinline__ float b2f(u16 u){
  union { float f; u32 i; } c; c.i = ((u32)u) << 16; return c.f;
}
__device__ __forceinline__ u16 f2b(float f){
  union { float f; u32 i; } c; c.f = f;
  u32 x = c.i;
  return (u16)((x + 0x7FFF + ((x >> 16) & 1)) >> 16);
}
__device__ __forceinline__ u32 pack2(float lo, float hi){
  return (u32)f2b(lo) | ((u32)f2b(hi) << 16);
}
// dtype probe via 64-lane ballot on ln1_g (~N(1,0.02)): bf16 -> all 64 high
// bytes 0x3F; f32 -> only odd u16s (~32). Threshold 48.
__device__ __forceinline__ int probe_bf16(const void* ln1g){
  const u16* lp = (const u16*)ln1g;
  unsigned long long m = __ballot((lp[threadIdx.x & 63] >> 8) == 0x3F);
  return (__popcll(m) > 48) ? 1 : 0;
}

// ---------------- convert float inputs -> f32 ws + Wout transpose, one dispatch ----------------
struct ConvArgs {
  const void* src[18];
  float* dst[18];
  int n[18];
  int blkoff[19];
};
__global__ void __launch_bounds__(256) k_convtrans(ConvArgs a, const void* __restrict__ wsrc,
                                                   const void* __restrict__ ln1g, u16* __restrict__ wt){
  __shared__ float ws_[64][65];
  int isb = probe_bf16(ln1g);
  int nconv = a.blkoff[18];
  int tid = threadIdx.x;
  if ((int)blockIdx.x < nconv){
    int bid = blockIdx.x;
    int t = 0;
    while (bid >= a.blkoff[t + 1]) t++;
    int base = (bid - a.blkoff[t]) * 1024 + tid;
    const u16* s16 = (const u16*)a.src[t];
    const float* s32 = (const float*)a.src[t];
    float* d = a.dst[t];
    int n = a.n[t];
    #pragma unroll
    for (int e = 0; e < 4; e++){
      int i = base + e * 256;
      if (i < n) d[i] = isb ? b2f(s16[i]) : s32[i];
    }
  } else {
    int v0 = (blockIdx.x - nconv) * 64;
    const u16* s16 = (const u16*)wsrc;
    const float* s32 = (const float*)wsrc;
    int vl = tid & 63;
    #pragma unroll
    for (int kk = 0; kk < 16; kk++){
      int k = kk * 4 + (tid >> 6);
      size_t idx = (size_t)k * VV + v0 + vl;
      ws_[vl][k] = isb ? b2f(s16[idx]) : s32[idx];
    }
    __syncthreads();
    #pragma unroll
    for (int pass = 0; pass < 16; pass++){
      int v2 = pass * 4 + (tid >> 6);
      int k = tid & 63;
      wt[(size_t)(v0 + v2) * 64 + k] = f2b(ws_[v2][k]);
    }
  }
}

// ---------------- embedding (reads raw tok/pos with in-kernel dtype) ----------------
__global__ void k_embed(const int* __restrict__ x, const void* __restrict__ tokr,
                        const void* __restrict__ posr, const void* __restrict__ ln1g,
                        float* __restrict__ h){
  int isb = probe_bf16(ln1g);
  int i = blockIdx.x * 256 + threadIdx.x;
  int r = i >> 6, c = i & 63;
  int t = r & (TT - 1);
  size_t ti = (size_t)x[r] * 64 + c;
  size_t pi = (size_t)t * 64 + c;
  float tv = isb ? b2f(((const u16*)tokr)[ti]) : ((const float*)tokr)[ti];
  float pv = isb ? b2f(((const u16*)posr)[pi]) : ((const float*)posr)[pi];
  h[i] = tv + pv;
}

// ---------------- qkv projection -> bf16 (q scaled, k permuted, v transposed) ----------------
__global__ void k_qkv(const float* __restrict__ h,
                      const float* __restrict__ wq, const float* __restrict__ bq,
                      const float* __restrict__ wk, const float* __restrict__ bk,
                      const float* __restrict__ wv, const float* __restrict__ bv,
                      u16* __restrict__ q16, u16* __restrict__ kp16, u16* __restrict__ vt16){
  __shared__ float hs[4][64];
  int tid = threadIdx.x;
  int row0 = blockIdx.x * 4;
  hs[tid >> 6][tid & 63] = h[row0 * 64 + tid];
  __syncthreads();
  int rr = tid >> 6, o = tid & 63;
  int head = o >> 3, d = o & 7;
  int row = row0 + rr;
  int b = row >> 10, t = row & (TT - 1);
  float aq = bq[head * 8 + d], ak = bk[head * 8 + d], av = bv[head * 8 + d];
  #pragma unroll
  for (int c = 0; c < 64; c++){
    float hv = hs[rr][c];
    aq += hv * wq[(head * 64 + c) * 8 + d];
    ak += hv * wk[(head * 64 + c) * 8 + d];
    av += hv * wv[(head * 64 + c) * 8 + d];
  }
  int bh = b * HH + head;
  q16[((size_t)bh * TT + t) * 8 + d] = f2b(aq * 0.35355339059327378f);  // fold 1/sqrt(8)
  int i = t * 8 + d;                                  // faithful reshape(B,H,D,T)
  kp16[((size_t)bh * TT + (i & 1023)) * 8 + (i >> 10)] = f2b(ak);
  vt16[((size_t)bh * 8 + d) * TT + t] = f2b(av);
}

// ---------------- MFMA causal attention + LN1 + residual, 8 waves = 8 heads ----------------
__global__ void __launch_bounds__(512) k_attn2(const u16* __restrict__ q16, const u16* __restrict__ kp16,
                                               const u16* __restrict__ vt16, const float* __restrict__ g,
                                               const float* __restrict__ be, float* __restrict__ h){
  __shared__ float ot[16][64];
  int tid = threadIdx.x;
  int w = tid >> 6;                  // head
  int lane = tid & 63;
  int lr = lane & 15, lg = lane >> 4;
  int b = blockIdx.y;
  int bh = b * HH + w;
  int tb = blockIdx.x * 16;
  int t_g = tb + lr;

  short8v qf = {0,0,0,0,0,0,0,0};
  if (lg == 0) qf = *(const short8v*)(q16 + ((size_t)bh * TT + tb + lr) * 8);

  float m = -1e30f, l = 0.f;
  f32x4 o = {0.f, 0.f, 0.f, 0.f};
  int nchunk = (tb >> 5) + 1;

  for (int c = 0; c < nchunk; c++){
    int s0 = c * 32;
    bool skipB = (s0 + 16 > tb + 15);
    short8v kA = {0,0,0,0,0,0,0,0}, kB = {0,0,0,0,0,0,0,0};
    if (lg == 0){
      kA = *(const short8v*)(kp16 + ((size_t)bh * TT + s0 + lr) * 8);
      if (!skipB) kB = *(const short8v*)(kp16 + ((size_t)bh * TT + s0 + 16 + lr) * 8);
    }
    f32x4 sA = __builtin_amdgcn_mfma_f32_16x16x32_bf16(kA, qf, (f32x4){0.f,0.f,0.f,0.f}, 0, 0, 0);
    f32x4 sB;
    if (!skipB)
      sB = __builtin_amdgcn_mfma_f32_16x16x32_bf16(kB, qf, (f32x4){0.f,0.f,0.f,0.f}, 0, 0, 0);
    else
      sB = (f32x4){-1e30f, -1e30f, -1e30f, -1e30f};

    if (s0 + 15 > tb){
      #pragma unroll
      for (int r = 0; r < 4; r++) if (s0 + lg * 4 + r > t_g) sA[r] = -1e30f;
    }
    if (!skipB && s0 + 31 > tb){
      #pragma unroll
      for (int r = 0; r < 4; r++) if (s0 + 16 + lg * 4 + r > t_g) sB[r] = -1e30f;
    }

    float tm = fmaxf(fmaxf(fmaxf(sA[0], sA[1]), fmaxf(sA[2], sA[3])),
                     fmaxf(fmaxf(sB[0], sB[1]), fmaxf(sB[2], sB[3])));
    tm = fmaxf(tm, __shfl_xor(tm, 16, 64));
    tm = fmaxf(tm, __shfl_xor(tm, 32, 64));
    float mn = fmaxf(m, tm);
    float fac = __expf(m - mn);
    l *= fac;
    {
      float f0 = __shfl(fac, lg * 4 + 0, 64);
      float f1 = __shfl(fac, lg * 4 + 1, 64);
      float f2 = __shfl(fac, lg * 4 + 2, 64);
      float f3 = __shfl(fac, lg * 4 + 3, 64);
      o[0] *= f0; o[1] *= f1; o[2] *= f2; o[3] *= f3;
    }
    f32x4 pA, pB;
    #pragma unroll
    for (int r = 0; r < 4; r++){ pA[r] = __expf(sA[r] - mn); pB[r] = __expf(sB[r] - mn); }
    float ls = pA[0] + pA[1] + pA[2] + pA[3] + pB[0] + pB[1] + pB[2] + pB[3];
    ls += __shfl_xor(ls, 16, 64);
    ls += __shfl_xor(ls, 32, 64);
    l += ls;
    m = mn;

    u32 a0 = pack2(pA[0], pA[1]), a1 = pack2(pA[2], pA[3]);
    u32 b0 = pack2(pB[0], pB[1]), b1v = pack2(pB[2], pB[3]);
    int src0 = ((2 * lg) & 3) * 16 + lr;
    int src1 = src0 + 16;
    u32 A0 = __shfl((int)a0, src0, 64), A1 = __shfl((int)a1, src0, 64);
    u32 A2 = __shfl((int)a0, src1, 64), A3 = __shfl((int)a1, src1, 64);
    u32 B0 = __shfl((int)b0, src0, 64), B1 = __shfl((int)b1v, src0, 64);
    u32 B2 = __shfl((int)b0, src1, 64), B3 = __shfl((int)b1v, src1, 64);
    union { u32 u[4]; short8v v; } pu;
    if (lg < 2){ pu.u[0] = A0; pu.u[1] = A1; pu.u[2] = A2; pu.u[3] = A3; }
    else       { pu.u[0] = B0; pu.u[1] = B1; pu.u[2] = B2; pu.u[3] = B3; }

    short8v vf = {0,0,0,0,0,0,0,0};
    if (lr < 8) vf = *(const short8v*)(vt16 + ((size_t)bh * 8 + lr) * TT + s0 + lg * 8);

    o = __builtin_amdgcn_mfma_f32_16x16x32_bf16(pu.v, vf, o, 0, 0, 0);
  }

  float linv = 1.f / l;
  float i0 = __shfl(linv, lg * 4 + 0, 64);
  float i1 = __shfl(linv, lg * 4 + 1, 64);
  float i2 = __shfl(linv, lg * 4 + 2, 64);
  float i3 = __shfl(linv, lg * 4 + 3, 64);
  if (lr < 8){
    ot[lg * 4 + 0][w * 8 + lr] = o[0] * i0;
    ot[lg * 4 + 1][w * 8 + lr] = o[1] * i1;
    ot[lg * 4 + 2][w * 8 + lr] = o[2] * i2;
    ot[lg * 4 + 3][w * 8 + lr] = o[3] * i3;
  }
  __syncthreads();

  // LN over channels + residual into h, 16 rows, 8 rows per pass
  #pragma unroll
  for (int pass = 0; pass < 2; pass++){
    int rl = (tid >> 6) + pass * 8;
    float x = ot[rl][lane];
    float s = x, sq = x * x;
    for (int msk = 32; msk; msk >>= 1){
      s += __shfl_xor(s, msk, 64);
      sq += __shfl_xor(sq, msk, 64);
    }
    float mu = s * (1.f / 64);
    float var = sq * (1.f / 64) - mu * mu;
    float rstd = rsqrtf(fmaxf(var, 0.f) + 1e-5f);
    h[((size_t)b * TT + tb + rl) * 64 + lane] += (x - mu) * rstd * g[lane] + be[lane];
  }
}

// ---------------- h += relu(LN2(h)@W1+b1)@W2 + b2 (+optional bf16 emit) ----------------
__global__ void k_ffn(float* __restrict__ h, const float* __restrict__ g, const float* __restrict__ bb,
                      const float* __restrict__ w1, const float* __restrict__ b1,
                      const float* __restrict__ w2, const float* __restrict__ b2,
                      u16* __restrict__ hbo, int last){
  __shared__ float z[8][64];
  __shared__ float a[8][256];
  int tid = threadIdx.x;
  int row0 = blockIdx.x * 8;
  {
    int rr = tid >> 5, cp = tid & 31;
    int c0 = cp * 2;
    const float* hp = h + (row0 + rr) * 64;
    float x0 = hp[c0], x1 = hp[c0 + 1];
    float s = x0 + x1, sq = x0 * x0 + x1 * x1;
    for (int msk = 16; msk; msk >>= 1){
      s += __shfl_xor(s, msk, 64);
      sq += __shfl_xor(sq, msk, 64);
    }
    float mu = s * (1.f / 64);
    float var = sq * (1.f / 64) - mu * mu;
    float rstd = rsqrtf(fmaxf(var, 0.f) + 1e-5f);
    z[rr][c0]     = (x0 - mu) * rstd * g[c0] + bb[c0];
    z[rr][c0 + 1] = (x1 - mu) * rstd * g[c0 + 1] + bb[c0 + 1];
  }
  __syncthreads();
  {
    int j = tid;
    float acc[8];
    float bj = b1[j];
    #pragma unroll
    for (int r = 0; r < 8; r++) acc[r] = bj;
    for (int c = 0; c < 64; c++){
      float w = w1[c * 256 + j];
      #pragma unroll
      for (int r = 0; r < 8; r++) acc[r] += z[r][c] * w;
    }
    #pragma unroll
    for (int r = 0; r < 8; r++) a[r][j] = fmaxf(acc[r], 0.f);
  }
  __syncthreads();
  #pragma unroll
  for (int half = 0; half < 2; half++){
    int oi = tid + half * 256;
    int r = oi >> 6, c = oi & 63;
    float acc = b2[c];
    for (int k = 0; k < 256; k++) acc += a[r][k] * w2[k * 64 + c];
    int gi = (row0 + r) * 64 + c;
    float nh = h[gi] + acc;
    h[gi] = nh;
    if (last) hbo[gi] = f2b(nh);
  }
}

// ---------------- logits^T-frag GEMM: mfma(W,h) -> f32x4 NT stores + softmax partials ----------------
__global__ void __launch_bounds__(256) k_logits(const u16* __restrict__ hb, const u16* __restrict__ wt,
                                                const float* __restrict__ bout, float* __restrict__ logits,
                                                float2* __restrict__ part){
  int tid = threadIdx.x;
  int wave = tid >> 6, lane = tid & 63;
  int lr = lane & 15, lg = lane >> 4;
  int row0 = blockIdx.x * 64;            // x fastest: consecutive blocks share W-tile
  int cb = blockIdx.y;
  int colw = cb * 256 + wave * 64;

  short8v hf[4][2];
  #pragma unroll
  for (int ri = 0; ri < 4; ri++)
    #pragma unroll
    for (int kk = 0; kk < 2; kk++)
      hf[ri][kk] = *(const short8v*)(hb + (row0 + ri * 16 + lr) * 64 + kk * 32 + lg * 8);

  short8v wfr[4][2];
  #pragma unroll
  for (int vi = 0; vi < 4; vi++)
    #pragma unroll
    for (int kk = 0; kk < 2; kk++)
      wfr[vi][kk] = *(const short8v*)(wt + (size_t)(colw + vi * 16 + lr) * 64 + kk * 32 + lg * 8);

  f32x4 acc[4][4];
  #pragma unroll
  for (int ri = 0; ri < 4; ri++)
    #pragma unroll
    for (int vi = 0; vi < 4; vi++)
      acc[ri][vi] = (f32x4){0.f, 0.f, 0.f, 0.f};

  #pragma unroll
  for (int ri = 0; ri < 4; ri++){
    #pragma unroll
    for (int vi = 0; vi < 4; vi++){
      acc[ri][vi] = __builtin_amdgcn_mfma_f32_16x16x32_bf16(wfr[vi][0], hf[ri][0], acc[ri][vi], 0, 0, 0);
      acc[ri][vi] = __builtin_amdgcn_mfma_f32_16x16x32_bf16(wfr[vi][1], hf[ri][1], acc[ri][vi], 0, 0, 0);
    }
  }

  f32x4 bo[4];
  #pragma unroll
  for (int vi = 0; vi < 4; vi++)
    bo[vi] = *(const f32x4*)(bout + colw + vi * 16 + lg * 4);

  __shared__ float2 wml[4][64];
  #pragma unroll
  for (int ri = 0; ri < 4; ri++){
    f32x4 vals[4];
    #pragma unroll
    for (int vi = 0; vi < 4; vi++){
      vals[vi] = acc[ri][vi] + bo[vi];
      __builtin_nontemporal_store(vals[vi],
        (f32x4*)(logits + (size_t)(row0 + ri * 16 + lr) * VV + colw + vi * 16 + lg * 4));
    }
    float mx = -1e30f;
    #pragma unroll
    for (int vi = 0; vi < 4; vi++)
      #pragma unroll
      for (int r = 0; r < 4; r++) mx = fmaxf(mx, vals[vi][r]);
    mx = fmaxf(mx, __shfl_xor(mx, 16, 64));
    mx = fmaxf(mx, __shfl_xor(mx, 32, 64));
    float sume = 0.f;
    #pragma unroll
    for (int vi = 0; vi < 4; vi++)
      #pragma unroll
      for (int r = 0; r < 4; r++) sume += __expf(vals[vi][r] - mx);
    sume += __shfl_xor(sume, 16, 64);
    sume += __shfl_xor(sume, 32, 64);
    if (lg == 0) wml[wave][ri * 16 + lr] = make_float2(mx, sume);
  }
  __syncthreads();
  if (tid < 64){
    float M = -1e30f;
    #pragma unroll
    for (int w = 0; w < 4; w++) M = fmaxf(M, wml[w][tid].x);
    float L = 0.f;
    #pragma unroll
    for (int w = 0; w < 4; w++){
      float2 p = wml[w][tid];
      L += p.y * __expf(p.x - M);
    }
    part[(size_t)cb * NR + row0 + tid] = make_float2(M, L);
  }
}

// ---------------- loss reduction ----------------
__global__ void k_loss(const float2* __restrict__ part, const float* __restrict__ logits,
                       const int* __restrict__ tgt, float* __restrict__ lpart){
  int row = blockIdx.x * 64 + (threadIdx.x & 63);
  float M = -1e30f;
  for (int j = 0; j < NCB; j++) M = fmaxf(M, part[(size_t)j * NR + row].x);
  float L = 0.f;
  for (int j = 0; j < NCB; j++){
    float2 p = part[(size_t)j * NR + row];
    L += p.y * __expf(p.x - M);
  }
  float lse = M + __logf(L);
  float tl = logits[(size_t)row * VV + tgt[row]];
  float nll = lse - tl;
  for (int msk = 32; msk; msk >>= 1) nll += __shfl_xor(nll, msk, 64);
  if ((threadIdx.x & 63) == 0) lpart[blockIdx.x] = nll;
}
__global__ void k_loss2(const float* __restrict__ lpart, float* __restrict__ out){
  int lane = threadIdx.x & 63;
  float s = lpart[lane] + lpart[lane + 64];
  for (int msk = 32; msk; msk >>= 1) s += __shfl_xor(s, msk, 64);
  if (lane == 0) out[NLOGIT] = s * (1.f / NR);
}

extern "C" void kernel_launch(void* const* d_in, const int* in_sizes, int n_in,
                              void* d_out, int out_size, void* d_ws, size_t ws_size,
                              hipStream_t stream){
  (void)in_sizes; (void)n_in; (void)out_size; (void)ws_size;
  const int* x = (const int*)d_in[0];
  const int* targets = (const int*)d_in[1];
  float* out = (float*)d_out;

  // tok(0)/pos(1) read raw by k_embed; Wout(16) by transpose path.
  static const int WN[18] = {0, 0, 16384, 256, 16384, 256, 16384, 256,
                             256, 256, 256, 256, 65536, 1024, 65536, 256, 0, 32000};
  char* ws = (char*)d_ws;
  size_t off = 0;
  auto alloc = [&](size_t bytes) -> void* {
    void* p = ws + off;
    off += (bytes + 255) & ~(size_t)255;
    return p;
  };
  float* wf[18];
  for (int i = 0; i < 18; i++) wf[i] = (float*)alloc((size_t)(WN[i] ? WN[i] : 1) * 4);
  float* h     = (float*)alloc((size_t)NR * 64 * 4);
  u16* q16     = (u16*)alloc((size_t)NR * 64 * 2);
  u16* kp16    = (u16*)alloc((size_t)NR * 64 * 2);
  u16* vt16    = (u16*)alloc((size_t)NR * 64 * 2);
  u16* hb      = (u16*)alloc((size_t)NR * 64 * 2);
  u16* wt16    = (u16*)alloc((size_t)2048000 * 2);
  float2* part = (float2*)alloc((size_t)NCB * NR * 8);
  float* lpart = (float*)alloc(128 * 4);

  ConvArgs ca;
  int blk = 0;
  for (int i = 0; i < 18; i++){
    ca.src[i] = d_in[2 + i];
    ca.dst[i] = wf[i];
    ca.n[i] = WN[i];
    ca.blkoff[i] = blk;
    blk += (WN[i] + 1023) / 1024;
  }
  ca.blkoff[18] = blk;
  hipLaunchKernelGGL(k_convtrans, dim3(blk + 500), dim3(256), 0, stream, ca, d_in[18], d_in[10], wt16);
  hipLaunchKernelGGL(k_embed, dim3(2048), dim3(256), 0, stream, x, d_in[2], d_in[3], d_in[10], h);

  for (int l = 0; l < NLAY; l++){
    hipLaunchKernelGGL(k_qkv, dim3(2048), dim3(256), 0, stream, h,
                       wf[2] + l * 4096, wf[3] + l * 64,
                       wf[4] + l * 4096, wf[5] + l * 64,
                       wf[6] + l * 4096, wf[7] + l * 64,
                       q16, kp16, vt16);
    hipLaunchKernelGGL(k_attn2, dim3(64, 8), dim3(512), 0, stream, q16, kp16, vt16,
                       wf[8] + l * 64, wf[9] + l * 64, h);
    hipLaunchKernelGGL(k_ffn, dim3(1024), dim3(256), 0, stream, h,
                       wf[10] + l * 64, wf[11] + l * 64,
                       wf[12] + l * 16384, wf[13] + l * 256,
                       wf[14] + l * 16384, wf[15] + l * 64,
                       hb, (l == NLAY - 1) ? 1 : 0);
  }

  hipLaunchKernelGGL(k_logits, dim3(128, NCB), dim3(256), 0, stream, hb, wt16, wf[17], out, part);
  hipLaunchKernelGGL(k_loss, dim3(128), dim3(64), 0, stream, part, out, targets, lpart);
  hipLaunchKernelGGL(k_loss2, dim3(1), dim3(64), 0, stream, lpart, out);
}